// Round 2
// baseline (569.939 us; speedup 1.0000x reference)
//
#include <hip/hip_runtime.h>

#define C_DIM 1920
#define HW 196
#define N_DIM 256
#define K_DIM 1000
#define BN_EPS 1e-5f
#define TOT_ROWS (N_DIM * C_DIM)      // 491520
#define POOL_BLOCKS 2048              // persistent: 8 blocks/CU, 8192 waves
#define POOL_WAVES (POOL_BLOCKS * 4)  // 8192 -> 60 rows/wave, unroll 2 -> 30 iters

// ---------------- Kernel 1: BN-affine + ReLU + mean pool (+ bias init of out) ----------------
// Persistent grid-stride; one wave per row per iteration, 2 rows in flight per wave.
// HW = 196 floats = 49 float4 -> lanes 0..48 each load one float4.
__global__ __launch_bounds__(256) void pool_bias_kernel(
    const float* __restrict__ x,
    const float* __restrict__ bn_w, const float* __restrict__ bn_b,
    const float* __restrict__ rmean, const float* __restrict__ rvar,
    const float* __restrict__ bias,
    float* __restrict__ pooled,   // [TOT_ROWS]
    float* __restrict__ out)      // [N_DIM * K_DIM]
{
    const int tid   = threadIdx.x;
    const int wave  = tid >> 6;
    const int lane  = tid & 63;
    const int gwave = blockIdx.x * 4 + wave;

    // Fused bias init: blocks 0..999 write out[:, blockIdx.x] = bias[blockIdx.x]
    if (blockIdx.x < K_DIM) {
        out[tid * K_DIM + blockIdx.x] = bias[blockIdx.x];   // tid == n
    }

    for (int p = gwave; p < TOT_ROWS; p += 2 * POOL_WAVES) {
        const int p2 = p + POOL_WAVES;   // TOT_ROWS/POOL_WAVES = 60 (even) -> always valid

        // Issue both rows' loads back-to-back (independent, 2 outstanding).
        float4 v1 = make_float4(0.f, 0.f, 0.f, 0.f);
        float4 v2 = make_float4(0.f, 0.f, 0.f, 0.f);
        const float4* xp1 = reinterpret_cast<const float4*>(x + (size_t)p  * HW);
        const float4* xp2 = reinterpret_cast<const float4*>(x + (size_t)p2 * HW);
        if (lane < 49) { v1 = xp1[lane]; v2 = xp2[lane]; }

        const int c1 = p  % C_DIM;
        const int c2 = p2 % C_DIM;
        const float sc1 = bn_w[c1] * rsqrtf(rvar[c1] + BN_EPS);
        const float sh1 = bn_b[c1] - sc1 * rmean[c1];
        const float sc2 = bn_w[c2] * rsqrtf(rvar[c2] + BN_EPS);
        const float sh2 = bn_b[c2] - sc2 * rmean[c2];

        float s1 = 0.f, s2 = 0.f;
        if (lane < 49) {
            s1 = fmaxf(fmaf(v1.x, sc1, sh1), 0.f) + fmaxf(fmaf(v1.y, sc1, sh1), 0.f)
               + fmaxf(fmaf(v1.z, sc1, sh1), 0.f) + fmaxf(fmaf(v1.w, sc1, sh1), 0.f);
            s2 = fmaxf(fmaf(v2.x, sc2, sh2), 0.f) + fmaxf(fmaf(v2.y, sc2, sh2), 0.f)
               + fmaxf(fmaf(v2.z, sc2, sh2), 0.f) + fmaxf(fmaf(v2.w, sc2, sh2), 0.f);
        }
        // Two independent shuffle-reduce chains, interleaved.
        #pragma unroll
        for (int off = 32; off > 0; off >>= 1) {
            s1 += __shfl_down(s1, off, 64);
            s2 += __shfl_down(s2, off, 64);
        }
        if (lane == 0) {
            pooled[p]  = s1 * (1.0f / (float)HW);
            pooled[p2] = s2 * (1.0f / (float)HW);
        }
    }
}

// ---------------- Kernel 2: fp32 GEMM logits += pooled @ weight^T (split-K, atomic) -----------
#define BM 64
#define BN 64
#define BK 16
#define KSPLIT 8
#define KCHUNK (C_DIM / KSPLIT)   // 240

__global__ __launch_bounds__(256) void gemm_kernel(
    const float* __restrict__ A,   // pooled [N_DIM][C_DIM]
    const float* __restrict__ B,   // weight [K_DIM][C_DIM]
    float* __restrict__ out)       // [N_DIM][K_DIM], pre-initialized with bias
{
    __shared__ __align__(16) float As[BK][BM + 4];
    __shared__ __align__(16) float Bs[BK][BN + 4];

    const int tid = threadIdx.x;
    const int tx  = tid & 15;        // col group (4 cols)
    const int ty  = tid >> 4;        // row group (4 rows)
    const int m0  = blockIdx.y * BM;
    const int n0  = blockIdx.x * BN;
    const int k0  = blockIdx.z * KCHUNK;

    const int lrow = tid >> 2;       // 0..63: tile row for staging
    const int lk4  = (tid & 3) * 4;  // 0,4,8,12: k offset for staging

    float acc[4][4] = {};

    const int brow   = n0 + lrow;
    const bool bok   = (brow < K_DIM);
    const float* Ag  = A + (size_t)(m0 + lrow) * C_DIM + k0 + lk4;
    const float* Bg  = B + (size_t)brow * C_DIM + k0 + lk4;

    for (int kt = 0; kt < KCHUNK; kt += BK) {
        float4 av = *reinterpret_cast<const float4*>(Ag + kt);
        float4 bv = make_float4(0.f, 0.f, 0.f, 0.f);
        if (bok) bv = *reinterpret_cast<const float4*>(Bg + kt);

        __syncthreads();
        As[lk4 + 0][lrow] = av.x; As[lk4 + 1][lrow] = av.y;
        As[lk4 + 2][lrow] = av.z; As[lk4 + 3][lrow] = av.w;
        Bs[lk4 + 0][lrow] = bv.x; Bs[lk4 + 1][lrow] = bv.y;
        Bs[lk4 + 2][lrow] = bv.z; Bs[lk4 + 3][lrow] = bv.w;
        __syncthreads();

        #pragma unroll
        for (int kk = 0; kk < BK; ++kk) {
            float4 a4 = *reinterpret_cast<const float4*>(&As[kk][ty * 4]);
            float4 b4 = *reinterpret_cast<const float4*>(&Bs[kk][tx * 4]);
            acc[0][0] = fmaf(a4.x, b4.x, acc[0][0]);
            acc[0][1] = fmaf(a4.x, b4.y, acc[0][1]);
            acc[0][2] = fmaf(a4.x, b4.z, acc[0][2]);
            acc[0][3] = fmaf(a4.x, b4.w, acc[0][3]);
            acc[1][0] = fmaf(a4.y, b4.x, acc[1][0]);
            acc[1][1] = fmaf(a4.y, b4.y, acc[1][1]);
            acc[1][2] = fmaf(a4.y, b4.z, acc[1][2]);
            acc[1][3] = fmaf(a4.y, b4.w, acc[1][3]);
            acc[2][0] = fmaf(a4.z, b4.x, acc[2][0]);
            acc[2][1] = fmaf(a4.z, b4.y, acc[2][1]);
            acc[2][2] = fmaf(a4.z, b4.z, acc[2][2]);
            acc[2][3] = fmaf(a4.z, b4.w, acc[2][3]);
            acc[3][0] = fmaf(a4.w, b4.x, acc[3][0]);
            acc[3][1] = fmaf(a4.w, b4.y, acc[3][1]);
            acc[3][2] = fmaf(a4.w, b4.z, acc[3][2]);
            acc[3][3] = fmaf(a4.w, b4.w, acc[3][3]);
        }
    }

    #pragma unroll
    for (int i = 0; i < 4; ++i) {
        const int row = m0 + ty * 4 + i;
        #pragma unroll
        for (int j = 0; j < 4; ++j) {
            const int col = n0 + tx * 4 + j;
            if (col < K_DIM)
                atomicAdd(&out[(size_t)row * K_DIM + col], acc[i][j]);
        }
    }
}

extern "C" void kernel_launch(void* const* d_in, const int* in_sizes, int n_in,
                              void* d_out, int out_size, void* d_ws, size_t ws_size,
                              hipStream_t stream) {
    const float* x      = (const float*)d_in[0];
    const float* bn_w   = (const float*)d_in[1];
    const float* bn_b   = (const float*)d_in[2];
    const float* rmean  = (const float*)d_in[3];
    const float* rvar   = (const float*)d_in[4];
    const float* weight = (const float*)d_in[5];
    const float* bias   = (const float*)d_in[6];
    float* out    = (float*)d_out;
    float* pooled = (float*)d_ws;   // N_DIM*C_DIM floats = 1.97 MB

    // Kernel 1: persistent, 2048 blocks (8/CU), one wave per row, 2 rows in flight.
    pool_bias_kernel<<<POOL_BLOCKS, 256, 0, stream>>>(x, bn_w, bn_b, rmean, rvar,
                                                      bias, pooled, out);

    // Kernel 2: tiled split-K GEMM (512 blocks) with atomic accumulation onto
    // bias-initialized out.
    dim3 grid((K_DIM + BN - 1) / BN /*16*/, N_DIM / BM /*4*/, KSPLIT /*8*/);
    gemm_kernel<<<grid, 256, 0, stream>>>(pooled, weight, out);
}

// Round 4
// 553.569 us; speedup vs baseline: 1.0296x; 1.0296x over previous
//
#include <hip/hip_runtime.h>

#define C_DIM 1920
#define HW 196
#define N_DIM 256
#define K_DIM 1000
#define BN_EPS 1e-5f
#define TOT_ROWS (N_DIM * C_DIM)      // 491520
#define POOL_BLOCKS 2048              // persistent: 8 blocks/CU, 8192 waves
#define POOL_WAVES (POOL_BLOCKS * 4)  // 8192 waves -> 60 rows/wave, unroll 4 -> 15 iters

typedef float floatx4 __attribute__((ext_vector_type(4)));   // native vec for nt-load

// ---------------- Kernel 1: BN-affine + ReLU + mean pool (+ coalesced bias init) ------------
// Persistent; 4 rows in flight per wave per iteration (4 independent load+reduce chains).
// HW = 196 floats = 49 float4 -> lanes 0..48 each load one float4 (contiguous 784 B/row).
__global__ __launch_bounds__(256) void pool_bias_kernel(
    const float* __restrict__ x,
    const float* __restrict__ bn_w, const float* __restrict__ bn_b,
    const float* __restrict__ rmean, const float* __restrict__ rvar,
    const float* __restrict__ bias,
    float* __restrict__ pooled,   // [TOT_ROWS]
    float* __restrict__ out)      // [N_DIM * K_DIM]
{
    const int tid   = threadIdx.x;
    const int wave  = tid >> 6;
    const int lane  = tid & 63;
    const int gwave = blockIdx.x * 4 + wave;

    // Coalesced bias init: block b (0..255) writes out row b as 250 float4s.
    if (blockIdx.x < N_DIM && tid < 250) {
        reinterpret_cast<float4*>(out + (size_t)blockIdx.x * K_DIM)[tid] =
            reinterpret_cast<const float4*>(bias)[tid];
    }

    for (int p = gwave; p < TOT_ROWS; p += 4 * POOL_WAVES) {
        const int pr[4] = { p, p + POOL_WAVES, p + 2 * POOL_WAVES, p + 3 * POOL_WAVES };

        // Issue all four rows' loads back-to-back (independent, 4 outstanding, nontemporal).
        floatx4 v[4];
        #pragma unroll
        for (int r = 0; r < 4; ++r) v[r] = (floatx4)0.f;
        if (lane < 49) {
            #pragma unroll
            for (int r = 0; r < 4; ++r) {
                const floatx4* xp = reinterpret_cast<const floatx4*>(x + (size_t)pr[r] * HW);
                v[r] = __builtin_nontemporal_load(xp + lane);
            }
        }

        float s[4];
        #pragma unroll
        for (int r = 0; r < 4; ++r) {
            const int c = pr[r] % C_DIM;
            const float sc = bn_w[c] * rsqrtf(rvar[c] + BN_EPS);
            const float sh = bn_b[c] - sc * rmean[c];
            float t = fmaxf(fmaf(v[r].x, sc, sh), 0.f) + fmaxf(fmaf(v[r].y, sc, sh), 0.f)
                    + fmaxf(fmaf(v[r].z, sc, sh), 0.f) + fmaxf(fmaf(v[r].w, sc, sh), 0.f);
            s[r] = (lane < 49) ? t : 0.f;
        }

        // Four independent shuffle-reduce chains, interleaved.
        #pragma unroll
        for (int off = 32; off > 0; off >>= 1) {
            #pragma unroll
            for (int r = 0; r < 4; ++r) s[r] += __shfl_down(s[r], off, 64);
        }
        if (lane == 0) {
            #pragma unroll
            for (int r = 0; r < 4; ++r) pooled[pr[r]] = s[r] * (1.0f / (float)HW);
        }
    }
}

// ---------------- Kernel 2: fp32 GEMM logits += pooled @ weight^T (split-K, atomic) -----------
#define BM 64
#define BN 64
#define BK 16
#define KSPLIT 8
#define KCHUNK (C_DIM / KSPLIT)   // 240

__global__ __launch_bounds__(256) void gemm_kernel(
    const float* __restrict__ A,   // pooled [N_DIM][C_DIM]
    const float* __restrict__ B,   // weight [K_DIM][C_DIM]
    float* __restrict__ out)       // [N_DIM][K_DIM], pre-initialized with bias
{
    __shared__ __align__(16) float As[BK][BM + 4];
    __shared__ __align__(16) float Bs[BK][BN + 4];

    const int tid = threadIdx.x;
    const int tx  = tid & 15;        // col group (4 cols)
    const int ty  = tid >> 4;        // row group (4 rows)
    const int m0  = blockIdx.y * BM;
    const int n0  = blockIdx.x * BN;
    const int k0  = blockIdx.z * KCHUNK;

    const int lrow = tid >> 2;       // 0..63: tile row for staging
    const int lk4  = (tid & 3) * 4;  // 0,4,8,12: k offset for staging

    float acc[4][4] = {};

    const int brow   = n0 + lrow;
    const bool bok   = (brow < K_DIM);
    const float* Ag  = A + (size_t)(m0 + lrow) * C_DIM + k0 + lk4;
    const float* Bg  = B + (size_t)brow * C_DIM + k0 + lk4;

    for (int kt = 0; kt < KCHUNK; kt += BK) {
        float4 av = *reinterpret_cast<const float4*>(Ag + kt);
        float4 bv = make_float4(0.f, 0.f, 0.f, 0.f);
        if (bok) bv = *reinterpret_cast<const float4*>(Bg + kt);

        __syncthreads();
        As[lk4 + 0][lrow] = av.x; As[lk4 + 1][lrow] = av.y;
        As[lk4 + 2][lrow] = av.z; As[lk4 + 3][lrow] = av.w;
        Bs[lk4 + 0][lrow] = bv.x; Bs[lk4 + 1][lrow] = bv.y;
        Bs[lk4 + 2][lrow] = bv.z; Bs[lk4 + 3][lrow] = bv.w;
        __syncthreads();

        #pragma unroll
        for (int kk = 0; kk < BK; ++kk) {
            float4 a4 = *reinterpret_cast<const float4*>(&As[kk][ty * 4]);
            float4 b4 = *reinterpret_cast<const float4*>(&Bs[kk][tx * 4]);
            acc[0][0] = fmaf(a4.x, b4.x, acc[0][0]);
            acc[0][1] = fmaf(a4.x, b4.y, acc[0][1]);
            acc[0][2] = fmaf(a4.x, b4.z, acc[0][2]);
            acc[0][3] = fmaf(a4.x, b4.w, acc[0][3]);
            acc[1][0] = fmaf(a4.y, b4.x, acc[1][0]);
            acc[1][1] = fmaf(a4.y, b4.y, acc[1][1]);
            acc[1][2] = fmaf(a4.y, b4.z, acc[1][2]);
            acc[1][3] = fmaf(a4.y, b4.w, acc[1][3]);
            acc[2][0] = fmaf(a4.z, b4.x, acc[2][0]);
            acc[2][1] = fmaf(a4.z, b4.y, acc[2][1]);
            acc[2][2] = fmaf(a4.z, b4.z, acc[2][2]);
            acc[2][3] = fmaf(a4.z, b4.w, acc[2][3]);
            acc[3][0] = fmaf(a4.w, b4.x, acc[3][0]);
            acc[3][1] = fmaf(a4.w, b4.y, acc[3][1]);
            acc[3][2] = fmaf(a4.w, b4.z, acc[3][2]);
            acc[3][3] = fmaf(a4.w, b4.w, acc[3][3]);
        }
    }

    #pragma unroll
    for (int i = 0; i < 4; ++i) {
        const int row = m0 + ty * 4 + i;
        #pragma unroll
        for (int j = 0; j < 4; ++j) {
            const int col = n0 + tx * 4 + j;
            if (col < K_DIM)
                atomicAdd(&out[(size_t)row * K_DIM + col], acc[i][j]);
        }
    }
}

extern "C" void kernel_launch(void* const* d_in, const int* in_sizes, int n_in,
                              void* d_out, int out_size, void* d_ws, size_t ws_size,
                              hipStream_t stream) {
    const float* x      = (const float*)d_in[0];
    const float* bn_w   = (const float*)d_in[1];
    const float* bn_b   = (const float*)d_in[2];
    const float* rmean  = (const float*)d_in[3];
    const float* rvar   = (const float*)d_in[4];
    const float* weight = (const float*)d_in[5];
    const float* bias   = (const float*)d_in[6];
    float* out    = (float*)d_out;
    float* pooled = (float*)d_ws;   // N_DIM*C_DIM floats = 1.97 MB

    // Kernel 1: persistent, 2048 blocks (8/CU), 4 rows in flight per wave.
    pool_bias_kernel<<<POOL_BLOCKS, 256, 0, stream>>>(x, bn_w, bn_b, rmean, rvar,
                                                      bias, pooled, out);

    // Kernel 2: tiled split-K GEMM (512 blocks) with atomic accumulation onto
    // bias-initialized out.
    dim3 grid((K_DIM + BN - 1) / BN /*16*/, N_DIM / BM /*4*/, KSPLIT /*8*/);
    gemm_kernel<<<grid, 256, 0, stream>>>(pooled, weight, out);
}